// Round 5
// baseline (391.710 us; speedup 1.0000x reference)
//
#include <hip/hip_runtime.h>
#include <math.h>

#define B_  16
#define C_  512
#define HW_ 3136
#define K_  128
#define CHW (C_ * HW_)

typedef __bf16 bf16x8_t __attribute__((ext_vector_type(8)));
typedef __bf16 bf16x4_t __attribute__((ext_vector_type(4)));
typedef __bf16 bf16x2_t __attribute__((ext_vector_type(2)));
typedef float floatx4  __attribute__((ext_vector_type(4)));

typedef const __attribute__((address_space(1))) void* gas_ptr;
typedef __attribute__((address_space(3))) void*       las_ptr;

static __device__ __forceinline__ unsigned short bfbits(__bf16 v) {
    return __builtin_bit_cast(unsigned short, v);
}

// ---- direct staging: 128x64 bf16 tile (rows x red), XOR-swizzled 16B units ----
// unit u: m=u>>3, slot=u&7; holds red-group kg = slot ^ (m&7). Row stride 128 B.
__device__ __forceinline__ void stage128x64(const __bf16* __restrict__ base, long ld,
                                            int row0, int rowmax, int k0,
                                            __bf16* lds, int t) {
    int w = t >> 6;
    #pragma unroll
    for (int i = 0; i < 4; ++i) {
        int u = i * 256 + t;
        int m = u >> 3, slot = u & 7;
        int kg = slot ^ (m & 7);
        int r = row0 + m; if (r > rowmax) r = rowmax;
        const __bf16* g = base + (long)r * ld + (k0 + kg * 8);
        __bf16* l = lds + (size_t)(i * 256 + w * 64) * 8;   // wave-uniform base
        __builtin_amdgcn_global_load_lds((gas_ptr)g, (las_ptr)l, 16, 0, 0);
    }
}

// ---- direct staging: 128x32 bf16 tile (rows x red), XOR-swizzled 16B units ----
// unit u: m=u>>2, slot=u&3; holds red-group kg = slot ^ ((m>>1)&3). Row stride 64 B.
// Read side: group q lives at slot q ^ ((row>>1)&3); for rows row = base16 + lm
// (base16 multiple of 16) this is q ^ ((lm>>1)&3) -> each 16-lane quarter-wave
// covers 8 distinct 16B positions x2 lanes = minimal bank occupancy.
__device__ __forceinline__ void stage128x32(const __bf16* __restrict__ base, long ld,
                                            int row0, int rowmax, int k0,
                                            __bf16* lds, int t) {
    int w = t >> 6;
    #pragma unroll
    for (int i = 0; i < 2; ++i) {
        int u = i * 256 + t;
        int m = u >> 2, slot = u & 3;
        int kg = slot ^ ((m >> 1) & 3);
        int r = row0 + m; if (r > rowmax) r = rowmax;
        const __bf16* g = base + (long)r * ld + (k0 + kg * 8);
        __bf16* l = lds + (size_t)(i * 256 + w * 64) * 8;   // wave-uniform base
        __builtin_amdgcn_global_load_lds((gas_ptr)g, (las_ptr)l, 16, 0, 0);
    }
}

// ---- transposed-staged B tile layout: 128 rows x 64 red, row stride 144 B ----
// element (row, r): byte = row*144 + (((r>>3) + row + (row>>3))&7)*16 + (r&7)*2
// k_phi B: LDS[n][c] from xbf2[c][n]
__device__ __forceinline__ void stage_tr_phi(const __bf16* __restrict__ src,
                                             int n0, int p0, char* Bs, int t) {
    int ng = t & 15;              // rows ng*8 .. ng*8+7
    int cp2 = (t >> 4) * 2;       // even red index in [0,32)
    #pragma unroll
    for (int ci = 0; ci < 2; ++ci) {
        int cc = cp2 + ci * 32;   // even, [0,64)
        const __bf16* g0 = src + (long)(p0 + cc) * HW_ + n0 + ng * 8;
        bf16x8_t v0 = *(const bf16x8_t*)g0;
        bf16x8_t v1 = *(const bf16x8_t*)(g0 + HW_);
        int r8 = cc >> 3, sub = (cc & 7) >> 1;
        #pragma unroll
        for (int j = 0; j < 8; ++j) {
            int row = ng * 8 + j;
            int slot = (r8 + row + (row >> 3)) & 7;
            unsigned int pr = ((unsigned int)bfbits(v1[j]) << 16) | bfbits(v0[j]);
            *(unsigned int*)(Bs + row * 144 + slot * 16 + sub * 4) = pr;
        }
    }
}

// k_t B: LDS[c][n] from xbf2 flat [n][c], scaled by inv_s[n]
__device__ __forceinline__ void stage_tr_t(const __bf16* __restrict__ src,
                                           const float* __restrict__ isrc,
                                           int c0, int p0, char* Bs, int t) {
    int cg = t & 15;
    int np2 = (t >> 4) * 2;
    #pragma unroll
    for (int ni = 0; ni < 2; ++ni) {
        int nn = np2 + ni * 32;
        int n = p0 + nn;                     // always < HW_ (7*448 = 3136)
        float s0 = isrc[n], s1 = isrc[n + 1];
        const __bf16* g0 = src + (long)n * C_ + c0 + cg * 8;
        bf16x8_t v0 = *(const bf16x8_t*)g0;
        bf16x8_t v1 = *(const bf16x8_t*)(g0 + C_);
        int r8 = nn >> 3, sub = (nn & 7) >> 1;
        #pragma unroll
        for (int j = 0; j < 8; ++j) {
            int row = cg * 8 + j;
            int slot = (r8 + row + (row >> 3)) & 7;
            __bf16 a0 = (__bf16)((float)v0[j] * s0);
            __bf16 a1 = (__bf16)((float)v1[j] * s1);
            unsigned int pr = ((unsigned int)bfbits(a1) << 16) | bfbits(a0);
            *(unsigned int*)(Bs + row * 144 + slot * 16 + sub * 4) = pr;
        }
    }
}

// ---- BK=64 step, A direct layout, B direct layout ----
__device__ __forceinline__ void mma_step64(const char* As, const char* Bs,
                                           floatx4 acc[4][4], int aoff, int boff,
                                           int q, int lxor) {
    #pragma unroll
    for (int h = 0; h < 2; ++h) {
        int s = (((h * 4 + q) ^ lxor) << 4);
        bf16x8_t af[4], bf[4];
        #pragma unroll
        for (int i = 0; i < 4; ++i) af[i] = *(const bf16x8_t*)(As + aoff + i * 2048 + s);
        #pragma unroll
        for (int i = 0; i < 4; ++i) bf[i] = *(const bf16x8_t*)(Bs + boff + i * 2048 + s);
        #pragma unroll
        for (int mi = 0; mi < 4; ++mi)
            #pragma unroll
            for (int ni = 0; ni < 4; ++ni)
                acc[mi][ni] = __builtin_amdgcn_mfma_f32_16x16x32_bf16(af[mi], bf[ni], acc[mi][ni], 0, 0, 0);
    }
}

// ---- BK=32 step, A direct 64B-row layout, B direct 64B-row layout ----
__device__ __forceinline__ void mma_step32(const char* As, const char* Bs,
                                           floatx4 acc[4][4], int lm, int q,
                                           int wrow, int wcol) {
    int slot = (q ^ ((lm >> 1) & 3)) << 4;
    int aoff = (wrow * 64 + lm) * 64 + slot;
    int boff = (wcol * 64 + lm) * 64 + slot;
    bf16x8_t af[4], bf[4];
    #pragma unroll
    for (int i = 0; i < 4; ++i) af[i] = *(const bf16x8_t*)(As + aoff + i * 1024);
    #pragma unroll
    for (int i = 0; i < 4; ++i) bf[i] = *(const bf16x8_t*)(Bs + boff + i * 1024);
    #pragma unroll
    for (int mi = 0; mi < 4; ++mi)
        #pragma unroll
        for (int ni = 0; ni < 4; ++ni)
            acc[mi][ni] = __builtin_amdgcn_mfma_f32_16x16x32_bf16(af[mi], bf[ni], acc[mi][ni], 0, 0, 0);
}

// ---- BK=64 step, A direct layout, B padded-rotation layout ----
__device__ __forceinline__ void mma_step_mix(const char* As, const char* Bs,
                                             floatx4 acc[4][4], int lm, int q,
                                             int wrow, int wcol) {
    int lxor = lm & 7;
    int aoff = (wrow * 64 + lm) * 128;
    #pragma unroll
    for (int h = 0; h < 2; ++h) {
        int g = h * 4 + q;
        int sa = (g ^ lxor) << 4;
        bf16x8_t af[4], bf[4];
        #pragma unroll
        for (int i = 0; i < 4; ++i) af[i] = *(const bf16x8_t*)(As + aoff + i * 2048 + sa);
        #pragma unroll
        for (int i = 0; i < 4; ++i) {
            int brow = wcol * 64 + i * 16 + lm;
            int slot = (g + brow + (brow >> 3)) & 7;
            bf[i] = *(const bf16x8_t*)(Bs + brow * 144 + slot * 16);
        }
        #pragma unroll
        for (int mi = 0; mi < 4; ++mi)
            #pragma unroll
            for (int ni = 0; ni < 4; ++ni)
                acc[mi][ni] = __builtin_amdgcn_mfma_f32_16x16x32_bf16(af[mi], bf[ni], acc[mi][ni], 0, 0, 0);
    }
}

// ================= small / prep kernels =================

__global__ __launch_bounds__(256) void k_pool(const float* __restrict__ y,
                                              float* __restrict__ pooled) {
    int bc = blockIdx.x;
    const float* yp = y + (long)bc * HW_;
    int t = threadIdx.x;
    float acc = 0.f;
    // 3136 floats = 784 float4
    #pragma unroll
    for (int i = 0; i < 4; ++i) {
        int n4 = t + i * 256;
        if (n4 < 784) {
            float4 v = *reinterpret_cast<const float4*>(yp + (long)n4 * 4);
            acc += v.x + v.y + v.z + v.w;
        }
    }
    #pragma unroll
    for (int off = 32; off > 0; off >>= 1) acc += __shfl_xor(acc, off, 64);
    __shared__ float red[4];
    if ((t & 63) == 0) red[t >> 6] = acc;
    __syncthreads();
    if (t == 0) pooled[bc] = (red[0] + red[1] + red[2] + red[3]) * (1.0f / HW_);
}

// one wave per (k, b): coalesced float4 dot + shuffle reduce
__global__ __launch_bounds__(64) void k_rou(const float* __restrict__ pooled,
                                            const float* __restrict__ rou_w,
                                            const float* __restrict__ rou_b,
                                            float* __restrict__ rou_y) {
    int k = blockIdx.x;      // 0..127
    int b = blockIdx.y;      // 0..15
    int lane = threadIdx.x;  // 0..63
    const float* pr = pooled + b * C_;
    const float* wr = rou_w + (long)k * C_;
    float acc = 0.f;
    #pragma unroll
    for (int i = 0; i < 2; ++i) {
        int c = (lane + i * 64) * 4;
        float4 w4 = *reinterpret_cast<const float4*>(wr + c);
        float4 p4 = *reinterpret_cast<const float4*>(pr + c);
        acc += w4.x * p4.x + w4.y * p4.y + w4.z * p4.z + w4.w * p4.w;
    }
    #pragma unroll
    for (int off = 32; off > 0; off >>= 1) acc += __shfl_xor(acc, off, 64);
    if (lane == 0) rou_y[b * K_ + k] = 1.0f / (1.0f + expf(-(acc + rou_b[k])));
}

__global__ __launch_bounds__(256) void k_cast8(const float* __restrict__ a,
                                               __bf16* __restrict__ o) {
    long i = ((long)blockIdx.x * 256 + threadIdx.x) * 8;
    float4 v0 = *reinterpret_cast<const float4*>(a + i);
    float4 v1 = *reinterpret_cast<const float4*>(a + i + 4);
    bf16x8_t r;
    r[0] = (__bf16)v0.x; r[1] = (__bf16)v0.y; r[2] = (__bf16)v0.z; r[3] = (__bf16)v0.w;
    r[4] = (__bf16)v1.x; r[5] = (__bf16)v1.y; r[6] = (__bf16)v1.z; r[7] = (__bf16)v1.w;
    *reinterpret_cast<bf16x8_t*>(o + i) = r;
}

// ================= MFMA GEMMs =================
// All GEMM K-loops use the single-barrier double-buffered prefetch structure:
//   prologue: STAGE(buf0, step0); barrier
//   loop s:   STAGE(buf[cur^1], s+1)  [issue loads first]
//             MFMA on buf[cur]        [covers the load latency]
//             barrier; cur ^= 1       [one vmcnt(0) drain per tile, post-compute]

// phi: relu(phi_w @ X^T + b) -> phi_kn[k][n], phi_nk[n][k]; fused s[k] sums.
__global__ __launch_bounds__(256) void k_phi_m(const __bf16* __restrict__ xbf2,
                                               const __bf16* __restrict__ pwbf,
                                               const float* __restrict__ phi_b,
                                               __bf16* __restrict__ phi_kn,
                                               __bf16* __restrict__ phi_nk,
                                               float* __restrict__ sbuf) {
    int b = blockIdx.y;
    int n0 = blockIdx.x * 128;
    __shared__ __attribute__((aligned(16))) char smem[2 * 34816];   // dbuf: As 16K + Bs 18K
    int t = threadIdx.x, w = t >> 6, lane = t & 63;
    int lm = lane & 15, q = lane >> 4;
    int wrow = w >> 1, wcol = w & 1;
    floatx4 acc[4][4];
    #pragma unroll
    for (int i = 0; i < 4; ++i)
        #pragma unroll
        for (int j = 0; j < 4; ++j) acc[i][j] = (floatx4){0.f, 0.f, 0.f, 0.f};

    const __bf16* Bb = xbf2 + (long)b * CHW;

    stage128x64(pwbf, C_, 0, K_ - 1, 0, (__bf16*)smem, t);
    stage_tr_phi(Bb, n0, 0, smem + 16384, t);
    __syncthreads();
    int cur = 0;
    #pragma unroll
    for (int s = 0; s < 8; ++s) {
        char* cb = smem + cur * 34816;
        if (s < 7) {
            char* nb = smem + (cur ^ 1) * 34816;
            int p0 = (s + 1) * 64;
            stage128x64(pwbf, C_, 0, K_ - 1, p0, (__bf16*)nb, t);
            stage_tr_phi(Bb, n0, p0, nb + 16384, t);
        }
        mma_step_mix(cb, cb + 16384, acc, lm, q, wrow, wcol);
        __syncthreads();
        cur ^= 1;
    }
    #pragma unroll
    for (int mi = 0; mi < 4; ++mi) {
        int kb = wrow * 64 + mi * 16 + q * 4;
        float4 pb = *reinterpret_cast<const float4*>(phi_b + kb);
        float pbv[4] = {pb.x, pb.y, pb.z, pb.w};
        float sv[4] = {0.f, 0.f, 0.f, 0.f};
        #pragma unroll
        for (int ni = 0; ni < 4; ++ni) {
            int n = n0 + wcol * 64 + ni * 16 + lm;
            if (n < HW_) {
                bf16x4_t pack;
                #pragma unroll
                for (int r = 0; r < 4; ++r) {
                    float v = fmaxf(acc[mi][ni][r] + pbv[r], 0.f);
                    __bf16 vb = (__bf16)v;
                    phi_kn[((long)b * K_ + kb + r) * HW_ + n] = vb;
                    pack[r] = vb;
                    sv[r] += v;
                }
                *reinterpret_cast<bf16x4_t*>(phi_nk + ((long)b * HW_ + n) * K_ + kb) = pack;
            }
        }
        #pragma unroll
        for (int r = 0; r < 4; ++r) {
            float v = sv[r];
            v += __shfl_xor(v, 1, 64); v += __shfl_xor(v, 2, 64);
            v += __shfl_xor(v, 4, 64); v += __shfl_xor(v, 8, 64);
            if (lm == 0) atomicAdd(&sbuf[b * K_ + kb + r], v);
        }
    }
}

// fused: D[n] -> inv_s[n]; scale phi_nk row in place -> P_nk
// 16 B/lane: 4 n-rows per wave, 16-lane-group shuffle reduce
__global__ __launch_bounds__(256) void k_d2(__bf16* __restrict__ phi_nk,
                                            const float* __restrict__ rou_y,
                                            const float* __restrict__ s,
                                            float* __restrict__ inv_s) {
    int b = blockIdx.y;
    __shared__ float ws[K_];
    int t = threadIdx.x;
    if (t < K_) ws[t] = rou_y[b * K_ + t] * s[b * K_ + t];
    __syncthreads();
    int w = t >> 6, lane = t & 63;
    int sub = lane >> 4, lm = lane & 15;
    int n = blockIdx.x * 16 + w * 4 + sub;
    __bf16* p = phi_nk + ((long)b * HW_ + n) * K_ + lm * 8;
    bf16x8_t v = *reinterpret_cast<bf16x8_t*>(p);
    float f[8];
    #pragma unroll
    for (int j = 0; j < 8; ++j) f[j] = (float)v[j];
    float d = 0.f;
    #pragma unroll
    for (int j = 0; j < 8; ++j) d += f[j] * ws[lm * 8 + j];
    d += __shfl_xor(d, 1, 64); d += __shfl_xor(d, 2, 64);
    d += __shfl_xor(d, 4, 64); d += __shfl_xor(d, 8, 64);
    float inv = rsqrtf(d + 1e-8f);
    bf16x8_t o;
    #pragma unroll
    for (int j = 0; j < 8; ++j) o[j] = (__bf16)(f[j] * inv);
    *reinterpret_cast<bf16x8_t*>(p) = o;
    if (lm == 0) inv_s[b * HW_ + n] = inv;
}

// t_part[nch][b][k][c] = sum_{n in chunk} phi_kn[k][n] * (x_trans[n][c]*inv_s[n])
__global__ __launch_bounds__(256) void k_t_m(const __bf16* __restrict__ phi_kn,
                                             const __bf16* __restrict__ xbf2,
                                             const float* __restrict__ inv_s,
                                             float* __restrict__ t_part) {
    int gid = blockIdx.x;
    int rlo = gid & 7, cc4 = (gid >> 3) & 3, r8 = gid >> 5;
    int r = r8 * 8 + rlo;          // 0..111
    int b = r / 7, nch = r % 7;
    int c0 = cc4 * 128;
    __shared__ __attribute__((aligned(16))) char smem[2 * 34816];
    int t = threadIdx.x, w = t >> 6, lane = t & 63;
    int lm = lane & 15, q = lane >> 4;
    int wrow = w >> 1, wcol = w & 1;
    floatx4 acc[4][4];
    #pragma unroll
    for (int i = 0; i < 4; ++i)
        #pragma unroll
        for (int j = 0; j < 4; ++j) acc[i][j] = (floatx4){0.f, 0.f, 0.f, 0.f};

    const __bf16* Ab = phi_kn + (long)b * K_ * HW_;
    const __bf16* Bb = xbf2 + (long)b * CHW;
    const float* ib = inv_s + (long)b * HW_;

    int pstart = nch * 448;
    stage128x64(Ab, HW_, 0, K_ - 1, pstart, (__bf16*)smem, t);
    stage_tr_t(Bb, ib, c0, pstart, smem + 16384, t);
    __syncthreads();
    int cur = 0;
    #pragma unroll
    for (int s = 0; s < 7; ++s) {
        char* cb = smem + cur * 34816;
        if (s < 6) {
            char* nb = smem + (cur ^ 1) * 34816;
            int p0 = pstart + (s + 1) * 64;
            stage128x64(Ab, HW_, 0, K_ - 1, p0, (__bf16*)nb, t);
            stage_tr_t(Bb, ib, c0, p0, nb + 16384, t);
        }
        mma_step_mix(cb, cb + 16384, acc, lm, q, wrow, wcol);
        __syncthreads();
        cur ^= 1;
    }
    float* outp = t_part + ((long)nch * B_ + b) * K_ * C_;
    #pragma unroll
    for (int mi = 0; mi < 4; ++mi) {
        int kb = wrow * 64 + mi * 16 + q * 4;
        #pragma unroll
        for (int ni = 0; ni < 4; ++ni) {
            int c = c0 + wcol * 64 + ni * 16 + lm;
            #pragma unroll
            for (int rr = 0; rr < 4; ++rr)
                outp[(long)(kb + rr) * C_ + c] = acc[mi][ni][rr];
        }
    }
}

// reduce 7 split-K partials -> t_bf (bf16)
__global__ __launch_bounds__(256) void k_tred(const float* __restrict__ t_part,
                                              __bf16* __restrict__ t_bf) {
    const long BKC = (long)B_ * K_ * C_;
    long i = ((long)blockIdx.x * 256 + threadIdx.x) * 4;
    float4 s = *reinterpret_cast<const float4*>(t_part + i);
    #pragma unroll
    for (int p = 1; p < 7; ++p) {
        float4 v = *reinterpret_cast<const float4*>(t_part + p * BKC + i);
        s.x += v.x; s.y += v.y; s.z += v.z; s.w += v.w;
    }
    bf16x4_t o;
    o[0] = (__bf16)s.x; o[1] = (__bf16)s.y; o[2] = (__bf16)s.z; o[3] = (__bf16)s.w;
    *reinterpret_cast<bf16x4_t*>(t_bf + i) = o;
}

// tzT[c][k] = -rou[k] * sum_{c'} t_bf[k][c'] * zwbf[c][c']
__global__ __launch_bounds__(256) void k_tz_m(const __bf16* __restrict__ zwbf,
                                              const __bf16* __restrict__ t_bf,
                                              const float* __restrict__ rou_y,
                                              __bf16* __restrict__ tzT) {
    int b = blockIdx.y;
    int c0 = blockIdx.x * 128;
    __shared__ __attribute__((aligned(16))) char smem[2 * 32768];
    int t = threadIdx.x, w = t >> 6, lane = t & 63;
    int lm = lane & 15, q = lane >> 4;
    int wrow = w >> 1, wcol = w & 1;
    floatx4 acc[4][4];
    #pragma unroll
    for (int i = 0; i < 4; ++i)
        #pragma unroll
        for (int j = 0; j < 4; ++j) acc[i][j] = (floatx4){0.f, 0.f, 0.f, 0.f};

    const __bf16* Bb = t_bf + (long)b * K_ * C_;
    int lxor = lm & 7;
    int aoff = (wrow * 64 + lm) * 128;
    int boff = (wcol * 64 + lm) * 128;

    stage128x64(zwbf, C_, c0, C_ - 1, 0, (__bf16*)smem, t);
    stage128x64(Bb,   C_, 0, K_ - 1, 0, (__bf16*)(smem + 16384), t);
    __syncthreads();
    int cur = 0;
    #pragma unroll
    for (int s = 0; s < 8; ++s) {
        char* cb = smem + cur * 32768;
        if (s < 7) {
            char* nb = smem + (cur ^ 1) * 32768;
            int p0 = (s + 1) * 64;
            stage128x64(zwbf, C_, c0, C_ - 1, p0, (__bf16*)nb, t);
            stage128x64(Bb,   C_, 0, K_ - 1, p0, (__bf16*)(nb + 16384), t);
        }
        mma_step64(cb, cb + 16384, acc, aoff, boff, q, lxor);
        __syncthreads();
        cur ^= 1;
    }
    #pragma unroll
    for (int mi = 0; mi < 4; ++mi) {
        int c = c0 + wrow * 64 + mi * 16 + q * 4;
        #pragma unroll
        for (int ni = 0; ni < 4; ++ni) {
            int k = wcol * 64 + ni * 16 + lm;
            float rk = rou_y[b * K_ + k];
            #pragma unroll
            for (int rr = 0; rr < 4; ++rr)
                tzT[((long)b * C_ + c + rr) * K_ + k] = (__bf16)(-rk * acc[mi][ni][rr]);
        }
    }
}

// out[n][c] = bf16(x) + relu( X2@zeta^T + P_nk@tzT^T + zeta_b ). Swizzled 1D grid (1600).
// BK=32, dbuf 2x16KB = 32 KB LDS -> 5 blocks/CU for TLP latency hiding.
__global__ __launch_bounds__(256) void k_out_m(const __bf16* __restrict__ xbf2,
                                               const __bf16* __restrict__ zwbf,
                                               const __bf16* __restrict__ pnk,
                                               const __bf16* __restrict__ tzT,
                                               const float* __restrict__ zeta_b,
                                               float* __restrict__ out) {
    int gid = blockIdx.x;
    int rlo = gid & 7, cc4 = (gid >> 3) & 3, r8 = gid >> 5;
    int r = r8 * 8 + rlo;          // 0..399
    int b = r / 25, nt = r % 25;
    int n0 = nt * 128;
    int c0 = cc4 * 128;
    __shared__ __attribute__((aligned(16))) char smem[2 * 16384];
    int t = threadIdx.x, w = t >> 6, lane = t & 63;
    int lm = lane & 15, q = lane >> 4;
    int wrow = w >> 1, wcol = w & 1;
    floatx4 acc[4][4];
    #pragma unroll
    for (int i = 0; i < 4; ++i)
        #pragma unroll
        for (int j = 0; j < 4; ++j) acc[i][j] = (floatx4){0.f, 0.f, 0.f, 0.f};

    // unified 20-step BK=32 reduction: steps 0..15 = X2 @ zeta^T (red 512),
    // steps 16..19 = P_nk @ tzT^T (red 128, tzT pre-negated & rou-folded)
    const __bf16* A1 = xbf2 + (long)b * CHW;
    const __bf16* A2 = pnk + (long)b * (long)HW_ * K_;
    const __bf16* B2 = tzT + (long)b * (long)C_ * K_;

    stage128x32(A1,   C_, n0, HW_ - 1, 0, (__bf16*)smem, t);
    stage128x32(zwbf, C_, c0, C_ - 1, 0, (__bf16*)(smem + 8192), t);
    __syncthreads();
    int cur = 0;
    #pragma unroll
    for (int s = 0; s < 20; ++s) {
        char* cb = smem + cur * 16384;
        if (s < 19) {
            char* nb = smem + (cur ^ 1) * 16384;
            int sn = s + 1;
            if (sn < 16) {
                int p0 = sn * 32;
                stage128x32(A1,   C_, n0, HW_ - 1, p0, (__bf16*)nb, t);
                stage128x32(zwbf, C_, c0, C_ - 1, p0, (__bf16*)(nb + 8192), t);
            } else {
                int p0 = (sn - 16) * 32;
                stage128x32(A2, K_, n0, HW_ - 1, p0, (__bf16*)nb, t);
                stage128x32(B2, K_, c0, C_ - 1, p0, (__bf16*)(nb + 8192), t);
            }
        }
        mma_step32(cb, cb + 8192, acc, lm, q, wrow, wcol);
        __syncthreads();
        cur ^= 1;
    }
    // epilogue: LDS bounce, coalesced dwordx4 stores  (uses full 32 KB smem)
    float* ep = (float*)smem;                   // [32][132]
    const __bf16* xres = xbf2 + (long)b * CHW;
    int lr = t >> 3, lc = (t & 7) * 16;
    #pragma unroll
    for (int ch = 0; ch < 4; ++ch) {
        __syncthreads();
        if (wrow == (ch >> 1)) {
            #pragma unroll
            for (int mm = 0; mm < 2; ++mm) {
                int mi = (ch & 1) * 2 + mm;
                #pragma unroll
                for (int ni = 0; ni < 4; ++ni)
                    #pragma unroll
                    for (int rr = 0; rr < 4; ++rr)
                        ep[(mm * 16 + q * 4 + rr) * 132 + wcol * 64 + ni * 16 + lm] = acc[mi][ni][rr];
            }
        }
        __syncthreads();
        int n = n0 + ch * 32 + lr;
        if (n < HW_) {
            long rowbase = (long)n * C_ + c0 + lc;
            bf16x8_t x0 = *(const bf16x8_t*)(xres + rowbase);
            bf16x8_t x1 = *(const bf16x8_t*)(xres + rowbase + 8);
            float xv[16];
            #pragma unroll
            for (int j = 0; j < 8; ++j) { xv[j] = (float)x0[j]; xv[8 + j] = (float)x1[j]; }
            float* orow = out + (long)b * CHW + rowbase;
            #pragma unroll
            for (int jj = 0; jj < 4; ++jj) {
                float4 zb = *reinterpret_cast<const float4*>(zeta_b + c0 + lc + jj * 4);
                float4 e  = *reinterpret_cast<const float4*>(&ep[lr * 132 + lc + jj * 4]);
                float4 o;
                o.x = xv[jj * 4 + 0] + fmaxf(e.x + zb.x, 0.f);
                o.y = xv[jj * 4 + 1] + fmaxf(e.y + zb.y, 0.f);
                o.z = xv[jj * 4 + 2] + fmaxf(e.z + zb.z, 0.f);
                o.w = xv[jj * 4 + 3] + fmaxf(e.w + zb.w, 0.f);
                *reinterpret_cast<float4*>(orow + jj * 4) = o;
            }
        }
    }
}

extern "C" void kernel_launch(void* const* d_in, const int* in_sizes, int n_in,
                              void* d_out, int out_size, void* d_ws, size_t ws_size,
                              hipStream_t stream) {
    const float* x      = (const float*)d_in[0];
    const float* y      = (const float*)d_in[1];
    const float* phi_w  = (const float*)d_in[2];
    const float* phi_b  = (const float*)d_in[3];
    const float* rou_w  = (const float*)d_in[4];
    const float* rou_b  = (const float*)d_in[5];
    const float* zeta_w = (const float*)d_in[6];
    const float* zeta_b = (const float*)d_in[7];
    float* out = (float*)d_out;

    char* p = (char*)d_ws;
    __bf16* xbf2   = (__bf16*)p; p += (size_t)B_ * CHW * 2;              // 51.4 MB
    __bf16* phi_kn = (__bf16*)p; p += (size_t)B_ * K_ * HW_ * 2;         // 12.85 MB
    __bf16* phi_nk = (__bf16*)p; p += (size_t)B_ * K_ * HW_ * 2;         // 12.85 MB (-> P_nk)
    float*  t_part = (float*) p; p += (size_t)7 * B_ * K_ * C_ * 4;      // 29.4 MB
    __bf16* t_bf   = (__bf16*)p; p += (size_t)B_ * K_ * C_ * 2;         // 2.1 MB
    __bf16* tzT    = (__bf16*)p; p += (size_t)B_ * C_ * K_ * 2;         // 2.1 MB
    __bf16* pwbf   = (__bf16*)p; p += (size_t)K_ * C_ * 2;
    __bf16* zwbf   = (__bf16*)p; p += (size_t)C_ * C_ * 2;
    float*  pooled = (float*) p; p += (size_t)B_ * C_ * 4;
    float*  rou_y  = (float*) p; p += (size_t)B_ * K_ * 4;
    float*  sbuf   = (float*) p; p += (size_t)B_ * K_ * 4;
    float*  inv_s  = (float*) p; p += (size_t)B_ * HW_ * 4;

    hipMemsetAsync(sbuf, 0, B_ * K_ * sizeof(float), stream);

    k_pool <<<B_ * C_, 256, 0, stream>>>(y, pooled);
    k_rou  <<<dim3(K_, B_), 64, 0, stream>>>(pooled, rou_w, rou_b, rou_y);
    k_cast8<<<(K_ * C_) / 2048, 256, 0, stream>>>(phi_w, pwbf);
    k_cast8<<<(C_ * C_) / 2048, 256, 0, stream>>>(zeta_w, zwbf);
    k_cast8<<<(B_ * (long)CHW) / 2048, 256, 0, stream>>>(x, xbf2);
    k_phi_m<<<dim3(25, B_), 256, 0, stream>>>(xbf2, pwbf, phi_b, phi_kn, phi_nk, sbuf);
    k_d2   <<<dim3(HW_ / 16, B_), 256, 0, stream>>>(phi_nk, rou_y, sbuf, inv_s);
    k_t_m  <<<448, 256, 0, stream>>>(phi_kn, xbf2, inv_s, t_part);
    k_tred <<<(B_ * K_ * C_) / 1024, 256, 0, stream>>>(t_part, t_bf);
    k_tz_m <<<dim3(C_ / 128, B_), 256, 0, stream>>>(zwbf, t_bf, rou_y, tzT);
    k_out_m<<<1600, 256, 0, stream>>>(xbf2, zwbf, phi_nk, tzT, zeta_b, out);
}

// Round 6
// 391.172 us; speedup vs baseline: 1.0014x; 1.0014x over previous
//
#include <hip/hip_runtime.h>
#include <math.h>

#define B_  16
#define C_  512
#define HW_ 3136
#define K_  128
#define CHW (C_ * HW_)

typedef __bf16 bf16x8_t __attribute__((ext_vector_type(8)));
typedef __bf16 bf16x4_t __attribute__((ext_vector_type(4)));
typedef __bf16 bf16x2_t __attribute__((ext_vector_type(2)));
typedef float floatx4  __attribute__((ext_vector_type(4)));

typedef const __attribute__((address_space(1))) void* gas_ptr;
typedef __attribute__((address_space(3))) void*       las_ptr;

static __device__ __forceinline__ unsigned short bfbits(__bf16 v) {
    return __builtin_bit_cast(unsigned short, v);
}

// ---- direct staging: 128x64 bf16 tile (rows x red), XOR-swizzled 16B units ----
// unit u: m=u>>3, slot=u&7; holds red-group kg = slot ^ (m&7). Row stride 128 B.
// 4 global_load_lds (16B) per thread per call.
__device__ __forceinline__ void stage128x64(const __bf16* __restrict__ base, long ld,
                                            int row0, int rowmax, int k0,
                                            __bf16* lds, int t) {
    int w = t >> 6;
    #pragma unroll
    for (int i = 0; i < 4; ++i) {
        int u = i * 256 + t;
        int m = u >> 3, slot = u & 7;
        int kg = slot ^ (m & 7);
        int r = row0 + m; if (r > rowmax) r = rowmax;
        const __bf16* g = base + (long)r * ld + (k0 + kg * 8);
        __bf16* l = lds + (size_t)(i * 256 + w * 64) * 8;   // wave-uniform base
        __builtin_amdgcn_global_load_lds((gas_ptr)g, (las_ptr)l, 16, 0, 0);
    }
}

// ---- transposed-staged B tile layout: 128 rows x 64 red, row stride 144 B ----
// element (row, r): byte = row*144 + (((r>>3) + row + (row>>3))&7)*16 + (r&7)*2
// k_phi B: LDS[n][c] from xbf2[c][n]
__device__ __forceinline__ void stage_tr_phi(const __bf16* __restrict__ src,
                                             int n0, int p0, char* Bs, int t) {
    int ng = t & 15;              // rows ng*8 .. ng*8+7
    int cp2 = (t >> 4) * 2;       // even red index in [0,32)
    #pragma unroll
    for (int ci = 0; ci < 2; ++ci) {
        int cc = cp2 + ci * 32;   // even, [0,64)
        const __bf16* g0 = src + (long)(p0 + cc) * HW_ + n0 + ng * 8;
        bf16x8_t v0 = *(const bf16x8_t*)g0;
        bf16x8_t v1 = *(const bf16x8_t*)(g0 + HW_);
        int r8 = cc >> 3, sub = (cc & 7) >> 1;
        #pragma unroll
        for (int j = 0; j < 8; ++j) {
            int row = ng * 8 + j;
            int slot = (r8 + row + (row >> 3)) & 7;
            unsigned int pr = ((unsigned int)bfbits(v1[j]) << 16) | bfbits(v0[j]);
            *(unsigned int*)(Bs + row * 144 + slot * 16 + sub * 4) = pr;
        }
    }
}

// k_t B: LDS[c][n] from xbf2 flat [n][c], scaled by inv_s[n]
__device__ __forceinline__ void stage_tr_t(const __bf16* __restrict__ src,
                                           const float* __restrict__ isrc,
                                           int c0, int p0, char* Bs, int t) {
    int cg = t & 15;
    int np2 = (t >> 4) * 2;
    #pragma unroll
    for (int ni = 0; ni < 2; ++ni) {
        int nn = np2 + ni * 32;
        int n = p0 + nn;                     // always < HW_
        float s0 = isrc[n], s1 = isrc[n + 1];
        const __bf16* g0 = src + (long)n * C_ + c0 + cg * 8;
        bf16x8_t v0 = *(const bf16x8_t*)g0;
        bf16x8_t v1 = *(const bf16x8_t*)(g0 + C_);
        int r8 = nn >> 3, sub = (nn & 7) >> 1;
        #pragma unroll
        for (int j = 0; j < 8; ++j) {
            int row = cg * 8 + j;
            int slot = (r8 + row + (row >> 3)) & 7;
            __bf16 a0 = (__bf16)((float)v0[j] * s0);
            __bf16 a1 = (__bf16)((float)v1[j] * s1);
            unsigned int pr = ((unsigned int)bfbits(a1) << 16) | bfbits(a0);
            *(unsigned int*)(Bs + row * 144 + slot * 16 + sub * 4) = pr;
        }
    }
}

// ---- BK=64 step, A direct layout, B direct layout ----
__device__ __forceinline__ void mma_step64(const char* As, const char* Bs,
                                           floatx4 acc[4][4], int aoff, int boff,
                                           int q, int lxor) {
    #pragma unroll
    for (int h = 0; h < 2; ++h) {
        int s = (((h * 4 + q) ^ lxor) << 4);
        bf16x8_t af[4], bf[4];
        #pragma unroll
        for (int i = 0; i < 4; ++i) af[i] = *(const bf16x8_t*)(As + aoff + i * 2048 + s);
        #pragma unroll
        for (int i = 0; i < 4; ++i) bf[i] = *(const bf16x8_t*)(Bs + boff + i * 2048 + s);
        #pragma unroll
        for (int mi = 0; mi < 4; ++mi)
            #pragma unroll
            for (int ni = 0; ni < 4; ++ni)
                acc[mi][ni] = __builtin_amdgcn_mfma_f32_16x16x32_bf16(af[mi], bf[ni], acc[mi][ni], 0, 0, 0);
    }
}

// ---- BK=64 step, A direct layout, B padded-rotation layout ----
__device__ __forceinline__ void mma_step_mix(const char* As, const char* Bs,
                                             floatx4 acc[4][4], int lm, int q,
                                             int wrow, int wcol) {
    int lxor = lm & 7;
    int aoff = (wrow * 64 + lm) * 128;
    #pragma unroll
    for (int h = 0; h < 2; ++h) {
        int g = h * 4 + q;
        int sa = (g ^ lxor) << 4;
        bf16x8_t af[4], bf[4];
        #pragma unroll
        for (int i = 0; i < 4; ++i) af[i] = *(const bf16x8_t*)(As + aoff + i * 2048 + sa);
        #pragma unroll
        for (int i = 0; i < 4; ++i) {
            int brow = wcol * 64 + i * 16 + lm;
            int slot = (g + brow + (brow >> 3)) & 7;
            bf[i] = *(const bf16x8_t*)(Bs + brow * 144 + slot * 16);
        }
        #pragma unroll
        for (int mi = 0; mi < 4; ++mi)
            #pragma unroll
            for (int ni = 0; ni < 4; ++ni)
                acc[mi][ni] = __builtin_amdgcn_mfma_f32_16x16x32_bf16(af[mi], bf[ni], acc[mi][ni], 0, 0, 0);
    }
}

// ================= small / prep kernels =================

__global__ __launch_bounds__(256) void k_pool(const float* __restrict__ y,
                                              float* __restrict__ pooled) {
    int bc = blockIdx.x;
    const float* yp = y + (long)bc * HW_;
    int t = threadIdx.x;
    float acc = 0.f;
    #pragma unroll
    for (int i = 0; i < 4; ++i) {
        int n4 = t + i * 256;
        if (n4 < 784) {
            float4 v = *reinterpret_cast<const float4*>(yp + (long)n4 * 4);
            acc += v.x + v.y + v.z + v.w;
        }
    }
    #pragma unroll
    for (int off = 32; off > 0; off >>= 1) acc += __shfl_xor(acc, off, 64);
    __shared__ float red[4];
    if ((t & 63) == 0) red[t >> 6] = acc;
    __syncthreads();
    if (t == 0) pooled[bc] = (red[0] + red[1] + red[2] + red[3]) * (1.0f / HW_);
}

// one wave per (k, b): coalesced float4 dot + shuffle reduce
__global__ __launch_bounds__(64) void k_rou(const float* __restrict__ pooled,
                                            const float* __restrict__ rou_w,
                                            const float* __restrict__ rou_b,
                                            float* __restrict__ rou_y) {
    int k = blockIdx.x;
    int b = blockIdx.y;
    int lane = threadIdx.x;
    const float* pr = pooled + b * C_;
    const float* wr = rou_w + (long)k * C_;
    float acc = 0.f;
    #pragma unroll
    for (int i = 0; i < 2; ++i) {
        int c = (lane + i * 64) * 4;
        float4 w4 = *reinterpret_cast<const float4*>(wr + c);
        float4 p4 = *reinterpret_cast<const float4*>(pr + c);
        acc += w4.x * p4.x + w4.y * p4.y + w4.z * p4.z + w4.w * p4.w;
    }
    #pragma unroll
    for (int off = 32; off > 0; off >>= 1) acc += __shfl_xor(acc, off, 64);
    if (lane == 0) rou_y[b * K_ + k] = 1.0f / (1.0f + expf(-(acc + rou_b[k])));
}

__global__ __launch_bounds__(256) void k_cast8(const float* __restrict__ a,
                                               __bf16* __restrict__ o) {
    long i = ((long)blockIdx.x * 256 + threadIdx.x) * 8;
    float4 v0 = *reinterpret_cast<const float4*>(a + i);
    float4 v1 = *reinterpret_cast<const float4*>(a + i + 4);
    bf16x8_t r;
    r[0] = (__bf16)v0.x; r[1] = (__bf16)v0.y; r[2] = (__bf16)v0.z; r[3] = (__bf16)v0.w;
    r[4] = (__bf16)v1.x; r[5] = (__bf16)v1.y; r[6] = (__bf16)v1.z; r[7] = (__bf16)v1.w;
    *reinterpret_cast<bf16x8_t*>(o + i) = r;
}

// ================= MFMA GEMMs =================

// phi: relu(phi_w @ X^T + b) -> phi_kn[k][n], phi_nk[n][k]; fused s[k] sums.
// (reg-staged B -> keep classic dbuf+syncthreads structure)
__global__ __launch_bounds__(256) void k_phi_m(const __bf16* __restrict__ xbf2,
                                               const __bf16* __restrict__ pwbf,
                                               const float* __restrict__ phi_b,
                                               __bf16* __restrict__ phi_kn,
                                               __bf16* __restrict__ phi_nk,
                                               float* __restrict__ sbuf) {
    int b = blockIdx.y;
    int n0 = blockIdx.x * 128;
    __shared__ __attribute__((aligned(16))) char smem[2 * 34816];
    int t = threadIdx.x, w = t >> 6, lane = t & 63;
    int lm = lane & 15, q = lane >> 4;
    int wrow = w >> 1, wcol = w & 1;
    floatx4 acc[4][4];
    #pragma unroll
    for (int i = 0; i < 4; ++i)
        #pragma unroll
        for (int j = 0; j < 4; ++j) acc[i][j] = (floatx4){0.f, 0.f, 0.f, 0.f};

    const __bf16* Bb = xbf2 + (long)b * CHW;

    stage128x64(pwbf, C_, 0, K_ - 1, 0, (__bf16*)smem, t);
    stage_tr_phi(Bb, n0, 0, smem + 16384, t);
    __syncthreads();
    int cur = 0;
    #pragma unroll
    for (int s = 0; s < 8; ++s) {
        char* cb = smem + cur * 34816;
        if (s < 7) {
            char* nb = smem + (cur ^ 1) * 34816;
            int p0 = (s + 1) * 64;
            stage128x64(pwbf, C_, 0, K_ - 1, p0, (__bf16*)nb, t);
            stage_tr_phi(Bb, n0, p0, nb + 16384, t);
        }
        mma_step_mix(cb, cb + 16384, acc, lm, q, wrow, wcol);
        __syncthreads();
        cur ^= 1;
    }
    #pragma unroll
    for (int mi = 0; mi < 4; ++mi) {
        int kb = wrow * 64 + mi * 16 + q * 4;
        float4 pb = *reinterpret_cast<const float4*>(phi_b + kb);
        float pbv[4] = {pb.x, pb.y, pb.z, pb.w};
        float sv[4] = {0.f, 0.f, 0.f, 0.f};
        #pragma unroll
        for (int ni = 0; ni < 4; ++ni) {
            int n = n0 + wcol * 64 + ni * 16 + lm;
            if (n < HW_) {
                bf16x4_t pack;
                #pragma unroll
                for (int r = 0; r < 4; ++r) {
                    float v = fmaxf(acc[mi][ni][r] + pbv[r], 0.f);
                    __bf16 vb = (__bf16)v;
                    phi_kn[((long)b * K_ + kb + r) * HW_ + n] = vb;
                    pack[r] = vb;
                    sv[r] += v;
                }
                *reinterpret_cast<bf16x4_t*>(phi_nk + ((long)b * HW_ + n) * K_ + kb) = pack;
            }
        }
        #pragma unroll
        for (int r = 0; r < 4; ++r) {
            float v = sv[r];
            v += __shfl_xor(v, 1, 64); v += __shfl_xor(v, 2, 64);
            v += __shfl_xor(v, 4, 64); v += __shfl_xor(v, 8, 64);
            if (lm == 0) atomicAdd(&sbuf[b * K_ + kb + r], v);
        }
    }
}

// fused: D[n] -> inv_s[n]; scale phi_nk row in place -> P_nk
__global__ __launch_bounds__(256) void k_d2(__bf16* __restrict__ phi_nk,
                                            const float* __restrict__ rou_y,
                                            const float* __restrict__ s,
                                            float* __restrict__ inv_s) {
    int b = blockIdx.y;
    __shared__ float ws[K_];
    int t = threadIdx.x;
    if (t < K_) ws[t] = rou_y[b * K_ + t] * s[b * K_ + t];
    __syncthreads();
    int w = t >> 6, lane = t & 63;
    int sub = lane >> 4, lm = lane & 15;
    int n = blockIdx.x * 16 + w * 4 + sub;
    __bf16* p = phi_nk + ((long)b * HW_ + n) * K_ + lm * 8;
    bf16x8_t v = *reinterpret_cast<bf16x8_t*>(p);
    float f[8];
    #pragma unroll
    for (int j = 0; j < 8; ++j) f[j] = (float)v[j];
    float d = 0.f;
    #pragma unroll
    for (int j = 0; j < 8; ++j) d += f[j] * ws[lm * 8 + j];
    d += __shfl_xor(d, 1, 64); d += __shfl_xor(d, 2, 64);
    d += __shfl_xor(d, 4, 64); d += __shfl_xor(d, 8, 64);
    float inv = rsqrtf(d + 1e-8f);
    bf16x8_t o;
    #pragma unroll
    for (int j = 0; j < 8; ++j) o[j] = (__bf16)(f[j] * inv);
    *reinterpret_cast<bf16x8_t*>(p) = o;
    if (lm == 0) inv_s[b * HW_ + n] = inv;
}

// t_part[nch][b][k][c] = sum_{n in chunk} phi_kn[k][n] * (x_trans[n][c]*inv_s[n])
// 4 n-chunks (12/12/12/13 steps of 64) -> grid exactly 256 blocks, 118 MB partials.
__global__ __launch_bounds__(256) void k_t_m(const __bf16* __restrict__ phi_kn,
                                             const __bf16* __restrict__ xbf2,
                                             const float* __restrict__ inv_s,
                                             float* __restrict__ t_part) {
    int gid = blockIdx.x;
    int rlo = gid & 7, cc4 = (gid >> 3) & 3, r8 = gid >> 5;
    int r = r8 * 8 + rlo;          // 0..63
    int b = r >> 2, nch = r & 3;
    int c0 = cc4 * 128;
    __shared__ __attribute__((aligned(16))) char smem[2 * 34816];
    int t = threadIdx.x, w = t >> 6, lane = t & 63;
    int lm = lane & 15, q = lane >> 4;
    int wrow = w >> 1, wcol = w & 1;
    floatx4 acc[4][4];
    #pragma unroll
    for (int i = 0; i < 4; ++i)
        #pragma unroll
        for (int j = 0; j < 4; ++j) acc[i][j] = (floatx4){0.f, 0.f, 0.f, 0.f};

    const __bf16* Ab = phi_kn + (long)b * K_ * HW_;
    const __bf16* Bb = xbf2 + (long)b * CHW;
    const float* ib = inv_s + (long)b * HW_;

    int steps = (nch == 3) ? 13 : 12;     // 12+12+12+13 = 49 steps of 64 = 3136
    int pstart = nch * 768;
    stage128x64(Ab, HW_, 0, K_ - 1, pstart, (__bf16*)smem, t);
    stage_tr_t(Bb, ib, c0, pstart, smem + 16384, t);
    __syncthreads();
    int cur = 0;
    for (int s = 0; s < steps; ++s) {
        char* cb = smem + cur * 34816;
        if (s < steps - 1) {
            char* nb = smem + (cur ^ 1) * 34816;
            int p0 = pstart + (s + 1) * 64;
            stage128x64(Ab, HW_, 0, K_ - 1, p0, (__bf16*)nb, t);
            stage_tr_t(Bb, ib, c0, p0, nb + 16384, t);
        }
        mma_step_mix(cb, cb + 16384, acc, lm, q, wrow, wcol);
        __syncthreads();
        cur ^= 1;
    }
    float* outp = t_part + ((long)nch * B_ + b) * K_ * C_;
    #pragma unroll
    for (int mi = 0; mi < 4; ++mi) {
        int kb = wrow * 64 + mi * 16 + q * 4;
        #pragma unroll
        for (int ni = 0; ni < 4; ++ni) {
            int c = c0 + wcol * 64 + ni * 16 + lm;
            #pragma unroll
            for (int rr = 0; rr < 4; ++rr)
                outp[(long)(kb + rr) * C_ + c] = acc[mi][ni][rr];
        }
    }
}

// reduce 4 split-K partials -> t_bf (bf16)
__global__ __launch_bounds__(256) void k_tred(const float* __restrict__ t_part,
                                              __bf16* __restrict__ t_bf) {
    const long BKC = (long)B_ * K_ * C_;
    long i = ((long)blockIdx.x * 256 + threadIdx.x) * 4;
    float4 s = *reinterpret_cast<const float4*>(t_part + i);
    #pragma unroll
    for (int p = 1; p < 4; ++p) {
        float4 v = *reinterpret_cast<const float4*>(t_part + p * BKC + i);
        s.x += v.x; s.y += v.y; s.z += v.z; s.w += v.w;
    }
    bf16x4_t o;
    o[0] = (__bf16)s.x; o[1] = (__bf16)s.y; o[2] = (__bf16)s.z; o[3] = (__bf16)s.w;
    *reinterpret_cast<bf16x4_t*>(t_bf + i) = o;
}

// tzT[c][k] = -rou[k] * sum_{c'} t_bf[k][c'] * zwbf[c][c']
// counted-vmcnt depth-2 pipeline (pure global_load_lds staging; 8 loads/stage).
__global__ __launch_bounds__(256) void k_tz_m(const __bf16* __restrict__ zwbf,
                                              const __bf16* __restrict__ t_bf,
                                              const float* __restrict__ rou_y,
                                              __bf16* __restrict__ tzT) {
    int b = blockIdx.y;
    int c0 = blockIdx.x * 128;
    __shared__ __attribute__((aligned(16))) char smem[2 * 32768];
    int t = threadIdx.x, w = t >> 6, lane = t & 63;
    int lm = lane & 15, q = lane >> 4;
    int wrow = w >> 1, wcol = w & 1;
    floatx4 acc[4][4];
    #pragma unroll
    for (int i = 0; i < 4; ++i)
        #pragma unroll
        for (int j = 0; j < 4; ++j) acc[i][j] = (floatx4){0.f, 0.f, 0.f, 0.f};

    const __bf16* Bb = t_bf + (long)b * K_ * C_;
    int lxor = lm & 7;
    int aoff = (wrow * 64 + lm) * 128;
    int boff = (wcol * 64 + lm) * 128;

    stage128x64(zwbf, C_, c0, C_ - 1, 0, (__bf16*)smem, t);
    stage128x64(Bb,   C_, 0, K_ - 1, 0, (__bf16*)(smem + 16384), t);
    {
        char* b1 = smem + 32768;
        stage128x64(zwbf, C_, c0, C_ - 1, 64, (__bf16*)b1, t);
        stage128x64(Bb,   C_, 0, K_ - 1, 64, (__bf16*)(b1 + 16384), t);
    }
    #pragma unroll
    for (int s = 0; s < 8; ++s) {
        char* cb = smem + (s & 1) * 32768;
        // wait for stage(s): 8 newer loads (stage(s+1)) may remain in flight
        if (s < 7) asm volatile("s_waitcnt vmcnt(8)" ::: "memory");
        else       asm volatile("s_waitcnt vmcnt(0)" ::: "memory");
        __builtin_amdgcn_s_barrier();            // all waves' stage(s) visible
        __builtin_amdgcn_sched_barrier(0);
        mma_step64(cb, cb + 16384, acc, aoff, boff, q, lxor);
        asm volatile("s_waitcnt lgkmcnt(0)" ::: "memory");
        __builtin_amdgcn_s_barrier();            // all waves done reading cb
        __builtin_amdgcn_sched_barrier(0);
        if (s + 2 <= 7) {
            int p0 = (s + 2) * 64;
            stage128x64(zwbf, C_, c0, C_ - 1, p0, (__bf16*)cb, t);
            stage128x64(Bb,   C_, 0, K_ - 1, p0, (__bf16*)(cb + 16384), t);
        }
    }
    #pragma unroll
    for (int mi = 0; mi < 4; ++mi) {
        int c = c0 + wrow * 64 + mi * 16 + q * 4;
        #pragma unroll
        for (int ni = 0; ni < 4; ++ni) {
            int k = wcol * 64 + ni * 16 + lm;
            float rk = rou_y[b * K_ + k];
            #pragma unroll
            for (int rr = 0; rr < 4; ++rr)
                tzT[((long)b * C_ + c + rr) * K_ + k] = (__bf16)(-rk * acc[mi][ni][rr]);
        }
    }
}

// out[n][c] = bf16(x) + relu( X2@zeta^T + P_nk@tzT^T + zeta_b ). Swizzled 1D grid (1600).
// BK=64 dbuf + counted-vmcnt raw-barrier depth-2 pipeline: no vmcnt(0) drain in the
// main loop; stage(t+2) reuses the buffer freed after MFMA(t).
__global__ __launch_bounds__(256) void k_out_m(const __bf16* __restrict__ xbf2,
                                               const __bf16* __restrict__ zwbf,
                                               const __bf16* __restrict__ pnk,
                                               const __bf16* __restrict__ tzT,
                                               const float* __restrict__ zeta_b,
                                               float* __restrict__ out) {
    int gid = blockIdx.x;
    int rlo = gid & 7, cc4 = (gid >> 3) & 3, r8 = gid >> 5;
    int r = r8 * 8 + rlo;          // 0..399
    int b = r / 25, nt = r % 25;
    int n0 = nt * 128;
    int c0 = cc4 * 128;
    __shared__ __attribute__((aligned(16))) char smem[2 * 32768];
    int t = threadIdx.x, w = t >> 6, lane = t & 63;
    int lm = lane & 15, q = lane >> 4;
    int wrow = w >> 1, wcol = w & 1;
    floatx4 acc[4][4];
    #pragma unroll
    for (int i = 0; i < 4; ++i)
        #pragma unroll
        for (int j = 0; j < 4; ++j) acc[i][j] = (floatx4){0.f, 0.f, 0.f, 0.f};

    int lxor = lm & 7;
    int aoff = (wrow * 64 + lm) * 128;
    int boff = (wcol * 64 + lm) * 128;

    // unified 10-step reduction: steps 0..7 = X2 @ zeta^T (red 512),
    // steps 8..9 = P_nk @ tzT^T (red 128, tzT pre-negated & rou-folded)
    const __bf16* A1 = xbf2 + (long)b * CHW;
    const __bf16* A2 = pnk + (long)b * (long)HW_ * K_;
    const __bf16* B2 = tzT + (long)b * (long)C_ * K_;

    // stage step s into buf (8 global_load_lds per thread)
    #define OUT_STAGE(s_, buf_)                                                     \
        do {                                                                        \
            if ((s_) < 8) {                                                         \
                stage128x64(A1,   C_, n0, HW_ - 1, (s_) * 64, (__bf16*)(buf_), t);  \
                stage128x64(zwbf, C_, c0, C_ - 1,  (s_) * 64, (__bf16*)((buf_) + 16384), t); \
            } else {                                                                \
                stage128x64(A2, K_, n0, HW_ - 1, ((s_) - 8) * 64, (__bf16*)(buf_), t); \
                stage128x64(B2, K_, c0, C_ - 1,  ((s_) - 8) * 64, (__bf16*)((buf_) + 16384), t); \
            }                                                                       \
        } while (0)

    OUT_STAGE(0, smem);
    OUT_STAGE(1, smem + 32768);
    #pragma unroll
    for (int s = 0; s < 10; ++s) {
        char* cb = smem + (s & 1) * 32768;
        // wait for stage(s); stage(s+1)'s 8 loads stay in flight (never drain to 0)
        if (s < 9) asm volatile("s_waitcnt vmcnt(8)" ::: "memory");
        else       asm volatile("s_waitcnt vmcnt(0)" ::: "memory");
        __builtin_amdgcn_s_barrier();            // all waves' stage(s) writes visible
        __builtin_amdgcn_sched_barrier(0);
        mma_step64(cb, cb + 16384, acc, aoff, boff, q, lxor);
        asm volatile("s_waitcnt lgkmcnt(0)" ::: "memory");
        __builtin_amdgcn_s_barrier();            // all waves done reading cb
        __builtin_amdgcn_sched_barrier(0);
        if (s + 2 <= 9) OUT_STAGE(s + 2, cb);    // overwrite freed buffer
    }
    #undef OUT_STAGE

    // epilogue: LDS bounce, coalesced dwordx4 stores
    float* ep = (float*)smem;                   // [32][132]
    const __bf16* xres = xbf2 + (long)b * CHW;
    int lr = t >> 3, lc = (t & 7) * 16;
    #pragma unroll
    for (int ch = 0; ch < 4; ++ch) {
        __syncthreads();
        if (wrow == (ch >> 1)) {
            #pragma unroll
            for (int mm = 0; mm < 2; ++mm) {
                int mi = (ch & 1) * 2 + mm;
                #pragma unroll
                for (int ni = 0; ni < 4; ++ni)
                    #pragma unroll
                    for (int rr = 0; rr < 4; ++rr)
                        ep[(mm * 16 + q * 4 + rr) * 132 + wcol * 64 + ni * 16 + lm] = acc[mi][ni][rr];
            }
        }
        __syncthreads();
        int n = n0 + ch * 32 + lr;
        if (n < HW_) {
            long rowbase = (long)n * C_ + c0 + lc;
            bf16x8_t x0 = *(const bf16x8_t*)(xres + rowbase);
            bf16x8_t x1 = *(const bf16x8_t*)(xres + rowbase + 8);
            float xv[16];
            #pragma unroll
            for (int j = 0; j < 8; ++j) { xv[j] = (float)x0[j]; xv[8 + j] = (float)x1[j]; }
            float* orow = out + (long)b * CHW + rowbase;
            #pragma unroll
            for (int jj = 0; jj < 4; ++jj) {
                float4 zb = *reinterpret_cast<const float4*>(zeta_b + c0 + lc + jj * 4);
                float4 e  = *reinterpret_cast<const float4*>(&ep[lr * 132 + lc + jj * 4]);
                float4 o;
                o.x = xv[jj * 4 + 0] + fmaxf(e.x + zb.x, 0.f);
                o.y = xv[jj * 4 + 1] + fmaxf(e.y + zb.y, 0.f);
                o.z = xv[jj * 4 + 2] + fmaxf(e.z + zb.z, 0.f);
                o.w = xv[jj * 4 + 3] + fmaxf(e.w + zb.w, 0.f);
                *reinterpret_cast<float4*>(orow + jj * 4) = o;
            }
        }
    }
}

extern "C" void kernel_launch(void* const* d_in, const int* in_sizes, int n_in,
                              void* d_out, int out_size, void* d_ws, size_t ws_size,
                              hipStream_t stream) {
    const float* x      = (const float*)d_in[0];
    const float* y      = (const float*)d_in[1];
    const float* phi_w  = (const float*)d_in[2];
    const float* phi_b  = (const float*)d_in[3];
    const float* rou_w  = (const float*)d_in[4];
    const float* rou_b  = (const float*)d_in[5];
    const float* zeta_w = (const float*)d_in[6];
    const float* zeta_b = (const float*)d_in[7];
    float* out = (float*)d_out;

    char* p = (char*)d_ws;
    __bf16* xbf2   = (__bf16*)p; p += (size_t)B_ * CHW * 2;              // 51.4 MB
    __bf16* phi_kn = (__bf16*)p; p += (size_t)B_ * K_ * HW_ * 2;         // 12.85 MB
    __bf16* phi_nk = (__bf16*)p; p += (size_t)B_ * K_ * HW_ * 2;         // 12.85 MB (-> P_nk)
    float*  t_part = (float*) p; p += (size_t)4 * B_ * K_ * C_ * 4;      // 16.8 MB
    __bf16* t_bf   = (__bf16*)p; p += (size_t)B_ * K_ * C_ * 2;         // 2.1 MB
    __bf16* tzT    = (__bf16*)p; p += (size_t)B_ * C_ * K_ * 2;         // 2.1 MB
    __bf16* pwbf   = (__bf16*)p; p += (size_t)K_ * C_ * 2;
    __bf16* zwbf   = (__bf16*)p; p += (size_t)C_ * C_ * 2;
    float*  pooled = (float*) p; p += (size_t)B_ * C_ * 4;
    float*  rou_y  = (float*) p; p += (size_t)B_ * K_ * 4;
    float*  sbuf   = (float*) p; p += (size_t)B_ * K_ * 4;
    float*  inv_s  = (float*) p; p += (size_t)B_ * HW_ * 4;

    hipMemsetAsync(sbuf, 0, B_ * K_ * sizeof(float), stream);

    k_pool <<<B_ * C_, 256, 0, stream>>>(y, pooled);
    k_rou  <<<dim3(K_, B_), 64, 0, stream>>>(pooled, rou_w, rou_b, rou_y);
    k_cast8<<<(K_ * C_) / 2048, 256, 0, stream>>>(phi_w, pwbf);
    k_cast8<<<(C_ * C_) / 2048, 256, 0, stream>>>(zeta_w, zwbf);
    k_cast8<<<(B_ * (long)CHW) / 2048, 256, 0, stream>>>(x, xbf2);
    k_phi_m<<<dim3(25, B_), 256, 0, stream>>>(xbf2, pwbf, phi_b, phi_kn, phi_nk, sbuf);
    k_d2   <<<dim3(HW_ / 16, B_), 256, 0, stream>>>(phi_nk, rou_y, sbuf, inv_s);
    k_t_m  <<<256, 256, 0, stream>>>(phi_kn, xbf2, inv_s, t_part);
    k_tred <<<(B_ * K_ * C_) / 1024, 256, 0, stream>>>(t_part, t_bf);
    k_tz_m <<<dim3(C_ / 128, B_), 256, 0, stream>>>(zwbf, t_bf, rou_y, tzT);
    k_out_m<<<1600, 256, 0, stream>>>(xbf2, zwbf, phi_nk, tzT, zeta_b, out);
}

// Round 8
// 387.395 us; speedup vs baseline: 1.0111x; 1.0097x over previous
//
#include <hip/hip_runtime.h>
#include <math.h>

#define B_  16
#define C_  512
#define HW_ 3136
#define K_  128
#define CHW (C_ * HW_)

typedef __bf16 bf16x8_t __attribute__((ext_vector_type(8)));
typedef __bf16 bf16x4_t __attribute__((ext_vector_type(4)));
typedef float floatx4  __attribute__((ext_vector_type(4)));

typedef const __attribute__((address_space(1))) void* gas_ptr;
typedef __attribute__((address_space(3))) void*       las_ptr;

static __device__ __forceinline__ unsigned short bfbits(__bf16 v) {
    return __builtin_bit_cast(unsigned short, v);
}

// ---- direct staging: 128x64 bf16 tile (rows x red), XOR-swizzled 16B units ----
// unit u: m=u>>3, slot=u&7; holds red-group kg = slot ^ (m&7). Row stride 128 B.
__device__ __forceinline__ void stage128x64(const __bf16* __restrict__ base, long ld,
                                            int row0, int rowmax, int k0,
                                            __bf16* lds, int t) {
    int w = t >> 6;
    #pragma unroll
    for (int i = 0; i < 4; ++i) {
        int u = i * 256 + t;
        int m = u >> 3, slot = u & 7;
        int kg = slot ^ (m & 7);
        int r = row0 + m; if (r > rowmax) r = rowmax;
        const __bf16* g = base + (long)r * ld + (k0 + kg * 8);
        __bf16* l = lds + (size_t)(i * 256 + w * 64) * 8;   // wave-uniform base
        __builtin_amdgcn_global_load_lds((gas_ptr)g, (las_ptr)l, 16, 0, 0);
    }
}

// ---- generalized transpose-staging into 144B-row rotation layout ----
// Builds LDS[row][red] tile (128 rows x 64 red) from src[red][row] where src is
// contiguous along 'row' (reads 16B along row dim for red pair (cc, cc+1)).
// element (row, r): byte = row*144 + (((r>>3) + row + (row>>3))&7)*16 + (r&7)*2
__device__ __forceinline__ void stage_tr(const __bf16* __restrict__ src, long ld,
                                         int r0, int p0, char* Bs, int t) {
    int rg = t & 15;              // rows rg*8 .. rg*8+7
    int pp2 = (t >> 4) * 2;       // even red index in [0,32)
    #pragma unroll
    for (int ci = 0; ci < 2; ++ci) {
        int cc = pp2 + ci * 32;   // even, [0,64)
        const __bf16* g0 = src + (long)(p0 + cc) * ld + r0 + rg * 8;
        bf16x8_t v0 = *(const bf16x8_t*)g0;
        bf16x8_t v1 = *(const bf16x8_t*)(g0 + ld);
        int r8 = cc >> 3, sub = (cc & 7) >> 1;
        #pragma unroll
        for (int j = 0; j < 8; ++j) {
            int row = rg * 8 + j;
            int slot = (r8 + row + (row >> 3)) & 7;
            unsigned int pr = ((unsigned int)bfbits(v1[j]) << 16) | bfbits(v0[j]);
            *(unsigned int*)(Bs + row * 144 + slot * 16 + sub * 4) = pr;
        }
    }
}

// ---- BK=64 step, A direct layout, B direct layout ----
__device__ __forceinline__ void mma_step64(const char* As, const char* Bs,
                                           floatx4 acc[4][4], int aoff, int boff,
                                           int q, int lxor) {
    #pragma unroll
    for (int h = 0; h < 2; ++h) {
        int s = (((h * 4 + q) ^ lxor) << 4);
        bf16x8_t af[4], bf[4];
        #pragma unroll
        for (int i = 0; i < 4; ++i) af[i] = *(const bf16x8_t*)(As + aoff + i * 2048 + s);
        #pragma unroll
        for (int i = 0; i < 4; ++i) bf[i] = *(const bf16x8_t*)(Bs + boff + i * 2048 + s);
        #pragma unroll
        for (int mi = 0; mi < 4; ++mi)
            #pragma unroll
            for (int ni = 0; ni < 4; ++ni)
                acc[mi][ni] = __builtin_amdgcn_mfma_f32_16x16x32_bf16(af[mi], bf[ni], acc[mi][ni], 0, 0, 0);
    }
}

// ---- BK=64 step, A direct layout, B rotation layout ----
__device__ __forceinline__ void mma_step_mix(const char* As, const char* Bs,
                                             floatx4 acc[4][4], int lm, int q,
                                             int wrow, int wcol) {
    int lxor = lm & 7;
    int aoff = (wrow * 64 + lm) * 128;
    #pragma unroll
    for (int h = 0; h < 2; ++h) {
        int g = h * 4 + q;
        int sa = (g ^ lxor) << 4;
        bf16x8_t af[4], bf[4];
        #pragma unroll
        for (int i = 0; i < 4; ++i) af[i] = *(const bf16x8_t*)(As + aoff + i * 2048 + sa);
        #pragma unroll
        for (int i = 0; i < 4; ++i) {
            int brow = wcol * 64 + i * 16 + lm;
            int slot = (g + brow + (brow >> 3)) & 7;
            bf[i] = *(const bf16x8_t*)(Bs + brow * 144 + slot * 16);
        }
        #pragma unroll
        for (int mi = 0; mi < 4; ++mi)
            #pragma unroll
            for (int ni = 0; ni < 4; ++ni)
                acc[mi][ni] = __builtin_amdgcn_mfma_f32_16x16x32_bf16(af[mi], bf[ni], acc[mi][ni], 0, 0, 0);
    }
}

// ---- BK=64 step, A rotation layout, B rotation layout ----
__device__ __forceinline__ void mma_step_rot2(const char* As, const char* Bs,
                                              floatx4 acc[4][4], int lm, int q,
                                              int wrow, int wcol) {
    #pragma unroll
    for (int h = 0; h < 2; ++h) {
        int g = h * 4 + q;
        bf16x8_t af[4], bf[4];
        #pragma unroll
        for (int i = 0; i < 4; ++i) {
            int arow = wrow * 64 + i * 16 + lm;
            int aslot = (g + arow + (arow >> 3)) & 7;
            af[i] = *(const bf16x8_t*)(As + arow * 144 + aslot * 16);
        }
        #pragma unroll
        for (int i = 0; i < 4; ++i) {
            int brow = wcol * 64 + i * 16 + lm;
            int bslot = (g + brow + (brow >> 3)) & 7;
            bf[i] = *(const bf16x8_t*)(Bs + brow * 144 + bslot * 16);
        }
        #pragma unroll
        for (int mi = 0; mi < 4; ++mi)
            #pragma unroll
            for (int ni = 0; ni < 4; ++ni)
                acc[mi][ni] = __builtin_amdgcn_mfma_f32_16x16x32_bf16(af[mi], bf[ni], acc[mi][ni], 0, 0, 0);
    }
}

// ================= small / prep kernels =================

__global__ __launch_bounds__(256) void k_pool(const float* __restrict__ y,
                                              float* __restrict__ pooled) {
    int bc = blockIdx.x;
    const float* yp = y + (long)bc * HW_;
    int t = threadIdx.x;
    float acc = 0.f;
    #pragma unroll
    for (int i = 0; i < 4; ++i) {
        int n4 = t + i * 256;
        if (n4 < 784) {
            float4 v = *reinterpret_cast<const float4*>(yp + (long)n4 * 4);
            acc += v.x + v.y + v.z + v.w;
        }
    }
    #pragma unroll
    for (int off = 32; off > 0; off >>= 1) acc += __shfl_xor(acc, off, 64);
    __shared__ float red[4];
    if ((t & 63) == 0) red[t >> 6] = acc;
    __syncthreads();
    if (t == 0) pooled[bc] = (red[0] + red[1] + red[2] + red[3]) * (1.0f / HW_);
}

// one wave per (k, b): coalesced float4 dot + shuffle reduce
__global__ __launch_bounds__(64) void k_rou(const float* __restrict__ pooled,
                                            const float* __restrict__ rou_w,
                                            const float* __restrict__ rou_b,
                                            float* __restrict__ rou_y) {
    int k = blockIdx.x;
    int b = blockIdx.y;
    int lane = threadIdx.x;
    const float* pr = pooled + b * C_;
    const float* wr = rou_w + (long)k * C_;
    float acc = 0.f;
    #pragma unroll
    for (int i = 0; i < 2; ++i) {
        int c = (lane + i * 64) * 4;
        float4 w4 = *reinterpret_cast<const float4*>(wr + c);
        float4 p4 = *reinterpret_cast<const float4*>(pr + c);
        acc += w4.x * p4.x + w4.y * p4.y + w4.z * p4.z + w4.w * p4.w;
    }
    #pragma unroll
    for (int off = 32; off > 0; off >>= 1) acc += __shfl_xor(acc, off, 64);
    if (lane == 0) rou_y[b * K_ + k] = 1.0f / (1.0f + expf(-(acc + rou_b[k])));
}

__global__ __launch_bounds__(256) void k_cast8(const float* __restrict__ a,
                                               __bf16* __restrict__ o) {
    long i = ((long)blockIdx.x * 256 + threadIdx.x) * 8;
    float4 v0 = *reinterpret_cast<const float4*>(a + i);
    float4 v1 = *reinterpret_cast<const float4*>(a + i + 4);
    bf16x8_t r;
    r[0] = (__bf16)v0.x; r[1] = (__bf16)v0.y; r[2] = (__bf16)v0.z; r[3] = (__bf16)v0.w;
    r[4] = (__bf16)v1.x; r[5] = (__bf16)v1.y; r[6] = (__bf16)v1.z; r[7] = (__bf16)v1.w;
    *reinterpret_cast<bf16x8_t*>(o + i) = r;
}

// ================= MFMA GEMMs =================
// GEMM K-loops: single-barrier double-buffered prefetch (round-1 verified best):
//   prologue STAGE(buf0); sync; loop { STAGE(buf^1, s+1); MFMA(buf); sync; flip }

// phi: relu(phi_w @ X^T + b) -> phi_nk[n][k] only; fused s[k] sums.
__global__ __launch_bounds__(256) void k_phi_m(const __bf16* __restrict__ xbf2,
                                               const __bf16* __restrict__ pwbf,
                                               const float* __restrict__ phi_b,
                                               __bf16* __restrict__ phi_nk,
                                               float* __restrict__ sbuf) {
    int b = blockIdx.y;
    int n0 = blockIdx.x * 128;
    __shared__ __attribute__((aligned(16))) char smem[2 * 34816];   // As 16K + Bs 18K
    int t = threadIdx.x, w = t >> 6, lane = t & 63;
    int lm = lane & 15, q = lane >> 4;
    int wrow = w >> 1, wcol = w & 1;
    floatx4 acc[4][4];
    #pragma unroll
    for (int i = 0; i < 4; ++i)
        #pragma unroll
        for (int j = 0; j < 4; ++j) acc[i][j] = (floatx4){0.f, 0.f, 0.f, 0.f};

    const __bf16* Bb = xbf2 + (long)b * CHW;   // [c][n] view

    stage128x64(pwbf, C_, 0, K_ - 1, 0, (__bf16*)smem, t);
    stage_tr(Bb, HW_, n0, 0, smem + 16384, t);
    __syncthreads();
    int cur = 0;
    #pragma unroll
    for (int s = 0; s < 8; ++s) {
        char* cb = smem + cur * 34816;
        if (s < 7) {
            char* nb = smem + (cur ^ 1) * 34816;
            int p0 = (s + 1) * 64;
            stage128x64(pwbf, C_, 0, K_ - 1, p0, (__bf16*)nb, t);
            stage_tr(Bb, HW_, n0, p0, nb + 16384, t);
        }
        mma_step_mix(cb, cb + 16384, acc, lm, q, wrow, wcol);
        __syncthreads();
        cur ^= 1;
    }
    #pragma unroll
    for (int mi = 0; mi < 4; ++mi) {
        int kb = wrow * 64 + mi * 16 + q * 4;
        float4 pb = *reinterpret_cast<const float4*>(phi_b + kb);
        float pbv[4] = {pb.x, pb.y, pb.z, pb.w};
        float sv[4] = {0.f, 0.f, 0.f, 0.f};
        #pragma unroll
        for (int ni = 0; ni < 4; ++ni) {
            int n = n0 + wcol * 64 + ni * 16 + lm;
            if (n < HW_) {
                bf16x4_t pack;
                #pragma unroll
                for (int r = 0; r < 4; ++r) {
                    float v = fmaxf(acc[mi][ni][r] + pbv[r], 0.f);
                    pack[r] = (__bf16)v;
                    sv[r] += v;
                }
                *reinterpret_cast<bf16x4_t*>(phi_nk + ((long)b * HW_ + n) * K_ + kb) = pack;
            }
        }
        #pragma unroll
        for (int r = 0; r < 4; ++r) {
            float v = sv[r];
            v += __shfl_xor(v, 1, 64); v += __shfl_xor(v, 2, 64);
            v += __shfl_xor(v, 4, 64); v += __shfl_xor(v, 8, 64);
            if (lm == 0) atomicAdd(&sbuf[b * K_ + kb + r], v);
        }
    }
}

// fused: D[n] -> inv_s[n]; scale phi_nk row in place -> P_nk
// 16 B/lane: 4 n-rows per wave, 16-lane-group shuffle reduce
__global__ __launch_bounds__(256) void k_d2(__bf16* __restrict__ phi_nk,
                                            const float* __restrict__ rou_y,
                                            const float* __restrict__ s,
                                            float* __restrict__ inv_s) {
    int b = blockIdx.y;
    __shared__ float ws[K_];
    int t = threadIdx.x;
    if (t < K_) ws[t] = rou_y[b * K_ + t] * s[b * K_ + t];
    __syncthreads();
    int w = t >> 6, lane = t & 63;
    int sub = lane >> 4, lm = lane & 15;
    int n = blockIdx.x * 16 + w * 4 + sub;
    __bf16* p = phi_nk + ((long)b * HW_ + n) * K_ + lm * 8;
    bf16x8_t v = *reinterpret_cast<bf16x8_t*>(p);
    float f[8];
    #pragma unroll
    for (int j = 0; j < 8; ++j) f[j] = (float)v[j];
    float d = 0.f;
    #pragma unroll
    for (int j = 0; j < 8; ++j) d += f[j] * ws[lm * 8 + j];
    d += __shfl_xor(d, 1, 64); d += __shfl_xor(d, 2, 64);
    d += __shfl_xor(d, 4, 64); d += __shfl_xor(d, 8, 64);
    float inv = rsqrtf(d + 1e-8f);
    bf16x8_t o;
    #pragma unroll
    for (int j = 0; j < 8; ++j) o[j] = (__bf16)(f[j] * inv);
    *reinterpret_cast<bf16x8_t*>(p) = o;
    if (lm == 0) inv_s[b * HW_ + n] = inv;
}

// t_part[nch][b][k][c] = sum_{n in chunk} P_nk[n][k] * x_trans[n][c]
// A = P_nk^T (tr-staged from [n][k]); B = x_trans^T (tr-staged from flat [n][c]).
// phi_kn buffer eliminated. 7 n-chunks of 448 -> 448 blocks (1.75/CU).
__global__ __launch_bounds__(256) void k_t_m(const __bf16* __restrict__ pnk,
                                             const __bf16* __restrict__ xbf2,
                                             float* __restrict__ t_part) {
    int gid = blockIdx.x;
    int rlo = gid & 7, cc4 = (gid >> 3) & 3, r8 = gid >> 5;
    int r = r8 * 8 + rlo;          // 0..111
    int b = r / 7, nch = r % 7;
    int c0 = cc4 * 128;
    __shared__ __attribute__((aligned(16))) char smem[2 * 36864];  // 2 x (18K + 18K)
    int t = threadIdx.x, w = t >> 6, lane = t & 63;
    int lm = lane & 15, q = lane >> 4;
    int wrow = w >> 1, wcol = w & 1;
    floatx4 acc[4][4];
    #pragma unroll
    for (int i = 0; i < 4; ++i)
        #pragma unroll
        for (int j = 0; j < 4; ++j) acc[i][j] = (floatx4){0.f, 0.f, 0.f, 0.f};

    const __bf16* Ab = pnk + (long)b * (long)HW_ * K_;  // [n][k]
    const __bf16* Bb = xbf2 + (long)b * CHW;            // flat [n][c]

    int pstart = nch * 448;
    stage_tr(Ab, K_, 0, pstart, smem, t);
    stage_tr(Bb, C_, c0, pstart, smem + 18432, t);
    __syncthreads();
    int cur = 0;
    #pragma unroll
    for (int s = 0; s < 7; ++s) {
        char* cb = smem + cur * 36864;
        if (s < 6) {
            char* nb = smem + (cur ^ 1) * 36864;
            int p0 = pstart + (s + 1) * 64;
            stage_tr(Ab, K_, 0, p0, nb, t);
            stage_tr(Bb, C_, c0, p0, nb + 18432, t);
        }
        mma_step_rot2(cb, cb + 18432, acc, lm, q, wrow, wcol);
        __syncthreads();
        cur ^= 1;
    }
    float* outp = t_part + ((long)nch * B_ + b) * K_ * C_;
    #pragma unroll
    for (int mi = 0; mi < 4; ++mi) {
        int kb = wrow * 64 + mi * 16 + q * 4;
        #pragma unroll
        for (int ni = 0; ni < 4; ++ni) {
            int c = c0 + wcol * 64 + ni * 16 + lm;
            #pragma unroll
            for (int rr = 0; rr < 4; ++rr)
                outp[(long)(kb + rr) * C_ + c] = acc[mi][ni][rr];
        }
    }
}

// reduce 7 split-K partials -> t_bf (bf16)
__global__ __launch_bounds__(256) void k_tred(const float* __restrict__ t_part,
                                              __bf16* __restrict__ t_bf) {
    const long BKC = (long)B_ * K_ * C_;
    long i = ((long)blockIdx.x * 256 + threadIdx.x) * 4;
    float4 s = *reinterpret_cast<const float4*>(t_part + i);
    #pragma unroll
    for (int p = 1; p < 7; ++p) {
        float4 v = *reinterpret_cast<const float4*>(t_part + p * BKC + i);
        s.x += v.x; s.y += v.y; s.z += v.z; s.w += v.w;
    }
    bf16x4_t o;
    o[0] = (__bf16)s.x; o[1] = (__bf16)s.y; o[2] = (__bf16)s.z; o[3] = (__bf16)s.w;
    *reinterpret_cast<bf16x4_t*>(t_bf + i) = o;
}

// tzT[c][k] = -rou[k] * sum_{c'} t_bf[k][c'] * zwbf[c][c']
__global__ __launch_bounds__(256) void k_tz_m(const __bf16* __restrict__ zwbf,
                                              const __bf16* __restrict__ t_bf,
                                              const float* __restrict__ rou_y,
                                              __bf16* __restrict__ tzT) {
    int b = blockIdx.y;
    int c0 = blockIdx.x * 128;
    __shared__ __attribute__((aligned(16))) char smem[2 * 32768];
    int t = threadIdx.x, w = t >> 6, lane = t & 63;
    int lm = lane & 15, q = lane >> 4;
    int wrow = w >> 1, wcol = w & 1;
    floatx4 acc[4][4];
    #pragma unroll
    for (int i = 0; i < 4; ++i)
        #pragma unroll
        for (int j = 0; j < 4; ++j) acc[i][j] = (floatx4){0.f, 0.f, 0.f, 0.f};

    const __bf16* Bb = t_bf + (long)b * K_ * C_;
    int lxor = lm & 7;
    int aoff = (wrow * 64 + lm) * 128;
    int boff = (wcol * 64 + lm) * 128;

    stage128x64(zwbf, C_, c0, C_ - 1, 0, (__bf16*)smem, t);
    stage128x64(Bb,   C_, 0, K_ - 1, 0, (__bf16*)(smem + 16384), t);
    __syncthreads();
    int cur = 0;
    #pragma unroll
    for (int s = 0; s < 8; ++s) {
        char* cb = smem + cur * 32768;
        if (s < 7) {
            char* nb = smem + (cur ^ 1) * 32768;
            int p0 = (s + 1) * 64;
            stage128x64(zwbf, C_, c0, C_ - 1, p0, (__bf16*)nb, t);
            stage128x64(Bb,   C_, 0, K_ - 1, p0, (__bf16*)(nb + 16384), t);
        }
        mma_step64(cb, cb + 16384, acc, aoff, boff, q, lxor);
        __syncthreads();
        cur ^= 1;
    }
    #pragma unroll
    for (int mi = 0; mi < 4; ++mi) {
        int c = c0 + wrow * 64 + mi * 16 + q * 4;
        #pragma unroll
        for (int ni = 0; ni < 4; ++ni) {
            int k = wcol * 64 + ni * 16 + lm;
            float rk = rou_y[b * K_ + k];
            #pragma unroll
            for (int rr = 0; rr < 4; ++rr)
                tzT[((long)b * C_ + c + rr) * K_ + k] = (__bf16)(-rk * acc[mi][ni][rr]);
        }
    }
}

// out[n][c] = bf16(x) + relu( X2@zeta^T + P_nk@tzT^T + zeta_b ). Swizzled 1D grid (1600).
// Round-1 structure (best measured: 67.3 us): BK=64, syncthreads dbuf, 10-step loop.
__global__ __launch_bounds__(256) void k_out_m(const __bf16* __restrict__ xbf2,
                                               const __bf16* __restrict__ zwbf,
                                               const __bf16* __restrict__ pnk,
                                               const __bf16* __restrict__ tzT,
                                               const float* __restrict__ zeta_b,
                                               float* __restrict__ out) {
    int gid = blockIdx.x;
    int rlo = gid & 7, cc4 = (gid >> 3) & 3, r8 = gid >> 5;
    int r = r8 * 8 + rlo;          // 0..399
    int b = r / 25, nt = r % 25;
    int n0 = nt * 128;
    int c0 = cc4 * 128;
    __shared__ __attribute__((aligned(16))) char smem[2 * 32768];
    int t = threadIdx.x, w = t >> 6, lane = t & 63;
    int lm = lane & 15, q = lane >> 4;
    int wrow = w >> 1, wcol = w & 1;
    floatx4 acc[4][4];
    #pragma unroll
    for (int i = 0; i < 4; ++i)
        #pragma unroll
        for (int j = 0; j < 4; ++j) acc[i][j] = (floatx4){0.f, 0.f, 0.f, 0.f};

    int lxor = lm & 7;
    int aoff = (wrow * 64 + lm) * 128;
    int boff = (wcol * 64 + lm) * 128;

    // unified 10-step reduction: steps 0..7 = X2 @ zeta^T (red 512),
    // steps 8..9 = P_nk @ tzT^T (red 128, tzT pre-negated & rou-folded)
    const __bf16* A1 = xbf2 + (long)b * CHW;
    const __bf16* A2 = pnk + (long)b * (long)HW_ * K_;
    const __bf16* B2 = tzT + (long)b * (long)C_ * K_;

    stage128x64(A1,   C_, n0, HW_ - 1, 0, (__bf16*)smem, t);
    stage128x64(zwbf, C_, c0, C_ - 1, 0, (__bf16*)(smem + 16384), t);
    __syncthreads();
    int cur = 0;
    #pragma unroll
    for (int s = 0; s < 10; ++s) {
        char* cb = smem + cur * 32768;
        if (s < 9) {
            char* nb = smem + (cur ^ 1) * 32768;
            int sn = s + 1;
            if (sn < 8) {
                int p0 = sn * 64;
                stage128x64(A1,   C_, n0, HW_ - 1, p0, (__bf16*)nb, t);
                stage128x64(zwbf, C_, c0, C_ - 1, p0, (__bf16*)(nb + 16384), t);
            } else {
                int p0 = (sn - 8) * 64;
                stage128x64(A2, K_, n0, HW_ - 1, p0, (__bf16*)nb, t);
                stage128x64(B2, K_, c0, C_ - 1, p0, (__bf16*)(nb + 16384), t);
            }
        }
        mma_step64(cb, cb + 16384, acc, aoff, boff, q, lxor);
        __syncthreads();
        cur ^= 1;
    }
    // epilogue: LDS bounce, coalesced dwordx4 stores
    float* ep = (float*)smem;                   // [32][132]
    const __bf16* xres = xbf2 + (long)b * CHW;
    int lr = t >> 3, lc = (t & 7) * 16;
    #pragma unroll
    for (int ch = 0; ch < 4; ++ch) {
        __syncthreads();
        if (wrow == (ch >> 1)) {
            #pragma unroll
            for (int mm = 0; mm < 2; ++mm) {
                int mi = (ch & 1) * 2 + mm;
                #pragma unroll
                for (int ni = 0; ni < 4; ++ni)
                    #pragma unroll
                    for (int rr = 0; rr < 4; ++rr)
                        ep[(mm * 16 + q * 4 + rr) * 132 + wcol * 64 + ni * 16 + lm] = acc[mi][ni][rr];
            }
        }
        __syncthreads();
        int n = n0 + ch * 32 + lr;
        if (n < HW_) {
            long rowbase = (long)n * C_ + c0 + lc;
            bf16x8_t x0 = *(const bf16x8_t*)(xres + rowbase);
            bf16x8_t x1 = *(const bf16x8_t*)(xres + rowbase + 8);
            float xv[16];
            #pragma unroll
            for (int j = 0; j < 8; ++j) { xv[j] = (float)x0[j]; xv[8 + j] = (float)x1[j]; }
            float* orow = out + (long)b * CHW + rowbase;
            #pragma unroll
            for (int jj = 0; jj < 4; ++jj) {
                float4 zb = *reinterpret_cast<const float4*>(zeta_b + c0 + lc + jj * 4);
                float4 e  = *reinterpret_cast<const float4*>(&ep[lr * 132 + lc + jj * 4]);
                float4 o;
                o.x = xv[jj * 4 + 0] + fmaxf(e.x + zb.x, 0.f);
                o.y = xv[jj * 4 + 1] + fmaxf(e.y + zb.y, 0.f);
                o.z = xv[jj * 4 + 2] + fmaxf(e.z + zb.z, 0.f);
                o.w = xv[jj * 4 + 3] + fmaxf(e.w + zb.w, 0.f);
                *reinterpret_cast<float4*>(orow + jj * 4) = o;
            }
        }
    }
}

extern "C" void kernel_launch(void* const* d_in, const int* in_sizes, int n_in,
                              void* d_out, int out_size, void* d_ws, size_t ws_size,
                              hipStream_t stream) {
    const float* x      = (const float*)d_in[0];
    const float* y      = (const float*)d_in[1];
    const float* phi_w  = (const float*)d_in[2];
    const float* phi_b  = (const float*)d_in[3];
    const float* rou_w  = (const float*)d_in[4];
    const float* rou_b  = (const float*)d_in[5];
    const float* zeta_w = (const float*)d_in[6];
    const float* zeta_b = (const float*)d_in[7];
    float* out = (float*)d_out;

    char* p = (char*)d_ws;
    __bf16* xbf2   = (__bf16*)p; p += (size_t)B_ * CHW * 2;              // 51.4 MB
    __bf16* phi_nk = (__bf16*)p; p += (size_t)B_ * K_ * HW_ * 2;         // 12.85 MB (-> P_nk)
    float*  t_part = (float*) p; p += (size_t)7 * B_ * K_ * C_ * 4;      // 29.4 MB
    __bf16* t_bf   = (__bf16*)p; p += (size_t)B_ * K_ * C_ * 2;         // 2.1 MB
    __bf16* tzT    = (__bf16*)p; p += (size_t)B_ * C_ * K_ * 2;         // 2.1 MB
    __bf16* pwbf   = (__bf16*)p; p += (size_t)K_ * C_ * 2;
    __bf16* zwbf   = (__bf16*)p; p += (size_t)C_ * C_ * 2;
    float*  pooled = (float*) p; p += (size_t)B_ * C_ * 4;
    float*  rou_y  = (float*) p; p += (size_t)B_ * K_ * 4;
    float*  sbuf   = (float*) p; p += (size_t)B_ * K_ * 4;
    float*  inv_s  = (float*) p; p += (size_t)B_ * HW_ * 4;

    hipMemsetAsync(sbuf, 0, B_ * K_ * sizeof(float), stream);

    k_pool <<<B_ * C_, 256, 0, stream>>>(y, pooled);
    k_rou  <<<dim3(K_, B_), 64, 0, stream>>>(pooled, rou_w, rou_b, rou_y);
    k_cast8<<<(K_ * C_) / 2048, 256, 0, stream>>>(phi_w, pwbf);
    k_cast8<<<(C_ * C_) / 2048, 256, 0, stream>>>(zeta_w, zwbf);
    k_cast8<<<(B_ * (long)CHW) / 2048, 256, 0, stream>>>(x, xbf2);
    k_phi_m<<<dim3(25, B_), 256, 0, stream>>>(xbf2, pwbf, phi_b, phi_nk, sbuf);
    k_d2   <<<dim3(HW_ / 16, B_), 256, 0, stream>>>(phi_nk, rou_y, sbuf, inv_s);
    k_t_m  <<<448, 256, 0, stream>>>(phi_nk, xbf2, t_part);
    k_tred <<<(B_ * K_ * C_) / 1024, 256, 0, stream>>>(t_part, t_bf);
    k_tz_m <<<dim3(C_ / 128, B_), 256, 0, stream>>>(zwbf, t_bf, rou_y, tzT);
    k_out_m<<<1600, 256, 0, stream>>>(xbf2, zwbf, phi_nk, tzT, zeta_b, out);
}